// Round 5
// baseline (82.934 us; speedup 1.0000x reference)
//
#include <hip/hip_runtime.h>
#include <math.h>

#define HDIM 4096
#define HK 16
#define DK 256
#define VE 512
#define QK 4096
#define VD 8192
#define NCHUNK 16
#define DPC 16           // DK / NCHUNK
#define EPS 1e-6f

// workspace float offsets
#define OFF_Q    0                        // 4096 (q linear)
#define OFF_K    4096                     // 4096
#define OFF_V    8192                     // 8192
#define OFF_AB   16384                    // 32 (alpha_lin 16, beta_lin 16)
#define OFF_KQ   16416                    // 16  (<q_h, k_h> per head)
#define OFF_OUT  16432                    // 8192
#define OFF_PQ   24624                    // NCHUNK*VD = 131072 partial Sq
#define OFF_PK   (24624 + NCHUNK*VD)      // 131072 partial Sk

__device__ __forceinline__ float sigmoidf_(float x) { return 1.f / (1.f + __expf(-x)); }
__device__ __forceinline__ float siluf_(float x)    { return x / (1.f + __expf(-x)); }

__device__ __forceinline__ void resolve_row(
    int row, const float* Wq, const float* Wk, const float* Wv,
    const float* Wa, const float* Wb, float* ws,
    const float4** w4, float** outp) {
  if (row < 4096)       { *w4 = (const float4*)(Wq + (size_t)row * HDIM);            *outp = ws + OFF_Q + row; }
  else if (row < 8192)  { int r = row - 4096;  *w4 = (const float4*)(Wk + (size_t)r * HDIM); *outp = ws + OFF_K + r; }
  else if (row < 16384) { int r = row - 8192;  *w4 = (const float4*)(Wv + (size_t)r * HDIM); *outp = ws + OFF_V + r; }
  else if (row < 16400) { int r = row - 16384; *w4 = (const float4*)(Wa + (size_t)r * HDIM); *outp = ws + OFF_AB + r; }
  else                  { int r = row - 16400; *w4 = (const float4*)(Wb + (size_t)r * HDIM); *outp = ws + OFF_AB + 16 + r; }
}

// ---------------- Kernel 1: fused GEMV over Wq/Wk/Wv/Wa/Wb -------------------
// FIXED resident grid: 2048 blocks = 8 blocks/CU co-resident (VGPR<=64),
// 32 waves/CU, zero block churn. Each wave grid-strides over rows
// (8192 waves, 16416 rows -> ~2 rows/wave). Plain load-use loop: 32 resident
// waves x ~2 outstanding 1KB loads = 64KB in flight/CU >> the ~22KB needed
// to sustain 24.6 GB/s/CU.
__global__ __launch_bounds__(256) void k1_gemv_all(
    const float* __restrict__ hvec,
    const float* __restrict__ Wq, const float* __restrict__ Wk,
    const float* __restrict__ Wv, const float* __restrict__ Wa,
    const float* __restrict__ Wb, float* __restrict__ ws) {
  int tid = threadIdx.x;
  int wave = tid >> 6, lane = tid & 63;
  int wid = blockIdx.x * 4 + wave;       // 0..8191
  const float4* h4 = (const float4*)hvec;

  for (int row = wid; row < 16416; row += 8192) {
    const float4* w4; float* outp;
    resolve_row(row, Wq, Wk, Wv, Wa, Wb, ws, &w4, &outp);
    float acc = 0.f;
#pragma unroll
    for (int j = 0; j < 16; ++j) {
      float4 w  = w4[j * 64 + lane];
      float4 hv = h4[j * 64 + lane];
      acc += w.x * hv.x + w.y * hv.y + w.z * hv.z + w.w * hv.w;
    }
#pragma unroll
    for (int off = 32; off; off >>= 1) acc += __shfl_xor(acc, off, 64);
    if (lane == 0) *outp = acc;
  }
}

// ------- Kernel B: state partials; per-head conv+silu+l2norm redundant -------
// grid 256 = 16 heads x 16 chunks; 512 threads (one per v column).
__global__ __launch_bounds__(512) void kB_state(
    const float* __restrict__ qcw, const float* __restrict__ kcw,
    const float* __restrict__ qc,  const float* __restrict__ kc,
    const float* __restrict__ state, float* __restrict__ ws) {
  int hh = blockIdx.x >> 4;
  int c  = blockIdx.x & 15;
  int tid = threadIdx.x;
  __shared__ float q1s[DK], k1s[DK];
  __shared__ float red[3][8];

  float a = 0.f, b = 0.f, cc = 0.f;
  if (tid < DK) {
    int i = hh * DK + tid;
    float q1 = qc[i*3+0]*qcw[i*4+0] + qc[i*3+1]*qcw[i*4+1] + qc[i*3+2]*qcw[i*4+2]
             + ws[OFF_Q + i]*qcw[i*4+3];
    q1 = siluf_(q1);
    float k1 = kc[i*3+0]*kcw[i*4+0] + kc[i*3+1]*kcw[i*4+1] + kc[i*3+2]*kcw[i*4+2]
             + ws[OFF_K + i]*kcw[i*4+3];
    k1 = siluf_(k1);
    q1s[tid] = q1; k1s[tid] = k1;
    a = q1 * q1; b = k1 * k1; cc = q1 * k1;
  }
#pragma unroll
  for (int off = 32; off; off >>= 1) {
    a  += __shfl_xor(a, off, 64);
    b  += __shfl_xor(b, off, 64);
    cc += __shfl_xor(cc, off, 64);
  }
  int wave = tid >> 6, lane = tid & 63;
  if (lane == 0) { red[0][wave] = a; red[1][wave] = b; red[2][wave] = cc; }
  __syncthreads();
  float ssq = 0.f, ssk = 0.f, skq = 0.f;
#pragma unroll
  for (int w = 0; w < 8; ++w) { ssq += red[0][w]; ssk += red[1][w]; skq += red[2][w]; }
  float rq = rsqrtf(ssq + EPS), rk = rsqrtf(ssk + EPS);
  if (c == 0 && tid == 0) ws[OFF_KQ + hh] = skq * rq * rk;

  int vv = tid;
  int d0 = c * DPC;
  float aq = 0.f, ak = 0.f;
#pragma unroll
  for (int t = 0; t < DPC; ++t) {
    int d = d0 + t;
    float s = state[((size_t)(hh * DK + d)) * VE + vv];
    aq += s * q1s[d];
    ak += s * k1s[d];
  }
  ws[OFF_PQ + c * VD + hh * VE + vv] = aq * rq;
  ws[OFF_PK + c * VD + hh * VE + vv] = ak * rk;
}

// ------ Kernel C: reduce partials + v-conv/silu + sigmoid + combine ----------
// 64 blocks x 128 threads; thread -> (head hh, column vv)
__global__ __launch_bounds__(128) void kC_combine(
    const float* __restrict__ vcw, const float* __restrict__ vc,
    float* __restrict__ ws) {
  int hh = blockIdx.x >> 2;
  int vv = (blockIdx.x & 3) * 128 + threadIdx.x;
  int col = hh * VE + vv;

  float Sq = 0.f, Sk = 0.f;
#pragma unroll
  for (int c = 0; c < NCHUNK; ++c) {
    Sq += ws[OFF_PQ + c * VD + col];
    Sk += ws[OFF_PK + c * VD + col];
  }
  float v1 = vc[col*3+0]*vcw[col*4+0] + vc[col*3+1]*vcw[col*4+1] + vc[col*3+2]*vcw[col*4+2]
           + ws[OFF_V + col]*vcw[col*4+3];
  float vh = siluf_(v1);
  float a  = sigmoidf_(ws[OFF_AB + hh]);
  float bb = sigmoidf_(ws[OFF_AB + 16 + hh]);
  float kq = ws[OFF_KQ + hh];
  // out = a*Sq + b*kq*(vh - a*Sk)
  ws[OFF_OUT + col] = a * Sq + bb * kq * (vh - a * Sk);
}

// --------------- Kernel D: output GEMV  d_out = Wo @ out ---------------------
// wave per row, 4 waves/block, 4096 rows -> 1024 blocks = 4 blocks/CU, all
// co-resident (no churn). Plain low-VGPR loop for max residency.
__global__ __launch_bounds__(256) void kD_gemv_out(
    const float* __restrict__ Wo, const float* __restrict__ ws,
    float* __restrict__ dout) {
  int tid = threadIdx.x;
  int wave = tid >> 6, lane = tid & 63;
  int row = blockIdx.x * 4 + wave;
  const float4* r4 = (const float4*)(Wo + (size_t)row * VD);
  const float4* o4 = (const float4*)(ws + OFF_OUT);

  float acc = 0.f;
#pragma unroll
  for (int j = 0; j < 32; ++j) {
    float4 w  = r4[j * 64 + lane];
    float4 ov = o4[j * 64 + lane];
    acc += w.x * ov.x + w.y * ov.y + w.z * ov.z + w.w * ov.w;
  }
#pragma unroll
  for (int off = 32; off; off >>= 1) acc += __shfl_xor(acc, off, 64);
  if (lane == 0) dout[row] = acc;
}

extern "C" void kernel_launch(void* const* d_in, const int* in_sizes, int n_in,
                              void* d_out, int out_size, void* d_ws, size_t ws_size,
                              hipStream_t stream) {
  const float* hvec = (const float*)d_in[0];
  const float* Wq   = (const float*)d_in[1];
  const float* Wk   = (const float*)d_in[2];
  const float* Wv   = (const float*)d_in[3];
  const float* Wo   = (const float*)d_in[4];
  const float* Wa   = (const float*)d_in[5];
  const float* Wb   = (const float*)d_in[6];
  const float* qcw  = (const float*)d_in[7];
  const float* kcw  = (const float*)d_in[8];
  const float* vcw  = (const float*)d_in[9];
  const float* qc   = (const float*)d_in[10];
  const float* kc   = (const float*)d_in[11];
  const float* vc   = (const float*)d_in[12];
  const float* state= (const float*)d_in[13];
  float* ws  = (float*)d_ws;
  float* out = (float*)d_out;

  k1_gemv_all<<<2048, 256, 0, stream>>>(hvec, Wq, Wk, Wv, Wa, Wb, ws);
  kB_state<<<256, 512, 0, stream>>>(qcw, kcw, qc, kc, state, ws);
  kC_combine<<<64, 128, 0, stream>>>(vcw, vc, ws);
  kD_gemv_out<<<1024, 256, 0, stream>>>(Wo, ws, out);
}

// Round 6
// 73.003 us; speedup vs baseline: 1.1360x; 1.1360x over previous
//
#include <hip/hip_runtime.h>
#include <math.h>

#define HDIM 4096
#define HK 16
#define DK 256
#define VE 512
#define QK 4096
#define VD 8192
#define NCHUNK 16
#define DPC 16           // DK / NCHUNK
#define EPS 1e-6f

// workspace float offsets
#define OFF_Q    0                        // 4096 (q linear)
#define OFF_K    4096                     // 4096
#define OFF_V    8192                     // 8192
#define OFF_AB   16384                    // 32 (alpha_lin 16, beta_lin 16)
#define OFF_KQ   16416                    // 16  (<q_h, k_h> per head)
#define OFF_OUT  16432                    // 8192
#define OFF_PQ   24624                    // NCHUNK*VD = 131072 partial Sq
#define OFF_PK   (24624 + NCHUNK*VD)      // 131072 partial Sk

typedef float f4_t __attribute__((ext_vector_type(4)));

__device__ __forceinline__ float sigmoidf_(float x) { return 1.f / (1.f + __expf(-x)); }
__device__ __forceinline__ float siluf_(float x)    { return x / (1.f + __expf(-x)); }

__device__ __forceinline__ void resolve_row(
    int row, const float* Wq, const float* Wk, const float* Wv,
    const float* Wa, const float* Wb, float* ws,
    const float4** w4, float** outp) {
  if (row < 4096)       { *w4 = (const float4*)(Wq + (size_t)row * HDIM);            *outp = ws + OFF_Q + row; }
  else if (row < 8192)  { int r = row - 4096;  *w4 = (const float4*)(Wk + (size_t)r * HDIM); *outp = ws + OFF_K + r; }
  else if (row < 16384) { int r = row - 8192;  *w4 = (const float4*)(Wv + (size_t)r * HDIM); *outp = ws + OFF_V + r; }
  else if (row < 16400) { int r = row - 16384; *w4 = (const float4*)(Wa + (size_t)r * HDIM); *outp = ws + OFF_AB + r; }
  else                  { int r = row - 16400; *w4 = (const float4*)(Wb + (size_t)r * HDIM); *outp = ws + OFF_AB + 16 + r; }
}

// ---------------- Kernel 1: fused GEMV over Wq/Wk/Wv/Wa/Wb -------------------
// wave per row, 4 waves/block, 16416 rows. NORMAL (caching) loads — these
// weights (269 MB) are the streams we want resident in the 256 MiB L3.
__global__ __launch_bounds__(256) void k1_gemv_all(
    const float* __restrict__ hvec,
    const float* __restrict__ Wq, const float* __restrict__ Wk,
    const float* __restrict__ Wv, const float* __restrict__ Wa,
    const float* __restrict__ Wb, float* __restrict__ ws) {
  int tid = threadIdx.x;
  int wave = tid >> 6, lane = tid & 63;
  int row = blockIdx.x * 4 + wave;
  if (row >= 16416) return;

  const float4* w4; float* outp;
  resolve_row(row, Wq, Wk, Wv, Wa, Wb, ws, &w4, &outp);
  const float4* h4 = (const float4*)hvec;

  float acc = 0.f;
#pragma unroll
  for (int j = 0; j < 16; ++j) {
    float4 w  = w4[j * 64 + lane];
    float4 hv = h4[j * 64 + lane];
    acc += w.x * hv.x + w.y * hv.y + w.z * hv.z + w.w * hv.w;
  }
#pragma unroll
  for (int off = 32; off; off >>= 1) acc += __shfl_xor(acc, off, 64);
  if (lane == 0) *outp = acc;
}

// ------- Kernel B: state partials; per-head conv+silu+l2norm redundant -------
// grid 256 = 16 heads x 16 chunks; 512 threads (one per v column).
// state is read exactly once per iteration -> NON-TEMPORAL (keep L3 for weights).
__global__ __launch_bounds__(512) void kB_state(
    const float* __restrict__ qcw, const float* __restrict__ kcw,
    const float* __restrict__ qc,  const float* __restrict__ kc,
    const float* __restrict__ state, float* __restrict__ ws) {
  int hh = blockIdx.x >> 4;
  int c  = blockIdx.x & 15;
  int tid = threadIdx.x;
  __shared__ float q1s[DK], k1s[DK];
  __shared__ float red[3][8];

  float a = 0.f, b = 0.f, cc = 0.f;
  if (tid < DK) {
    int i = hh * DK + tid;
    float q1 = qc[i*3+0]*qcw[i*4+0] + qc[i*3+1]*qcw[i*4+1] + qc[i*3+2]*qcw[i*4+2]
             + ws[OFF_Q + i]*qcw[i*4+3];
    q1 = siluf_(q1);
    float k1 = kc[i*3+0]*kcw[i*4+0] + kc[i*3+1]*kcw[i*4+1] + kc[i*3+2]*kcw[i*4+2]
             + ws[OFF_K + i]*kcw[i*4+3];
    k1 = siluf_(k1);
    q1s[tid] = q1; k1s[tid] = k1;
    a = q1 * q1; b = k1 * k1; cc = q1 * k1;
  }
#pragma unroll
  for (int off = 32; off; off >>= 1) {
    a  += __shfl_xor(a, off, 64);
    b  += __shfl_xor(b, off, 64);
    cc += __shfl_xor(cc, off, 64);
  }
  int wave = tid >> 6, lane = tid & 63;
  if (lane == 0) { red[0][wave] = a; red[1][wave] = b; red[2][wave] = cc; }
  __syncthreads();
  float ssq = 0.f, ssk = 0.f, skq = 0.f;
#pragma unroll
  for (int w = 0; w < 8; ++w) { ssq += red[0][w]; ssk += red[1][w]; skq += red[2][w]; }
  float rq = rsqrtf(ssq + EPS), rk = rsqrtf(ssk + EPS);
  if (c == 0 && tid == 0) ws[OFF_KQ + hh] = skq * rq * rk;

  int vv = tid;
  int d0 = c * DPC;
  float aq = 0.f, ak = 0.f;
#pragma unroll
  for (int t = 0; t < DPC; ++t) {
    int d = d0 + t;
    float s = __builtin_nontemporal_load(state + ((size_t)(hh * DK + d)) * VE + vv);
    aq += s * q1s[d];
    ak += s * k1s[d];
  }
  ws[OFF_PQ + c * VD + hh * VE + vv] = aq * rq;
  ws[OFF_PK + c * VD + hh * VE + vv] = ak * rk;
}

// ------ Kernel C: reduce partials + v-conv/silu + sigmoid + combine ----------
// 64 blocks x 128 threads; thread -> (head hh, column vv)
__global__ __launch_bounds__(128) void kC_combine(
    const float* __restrict__ vcw, const float* __restrict__ vc,
    float* __restrict__ ws) {
  int hh = blockIdx.x >> 2;
  int vv = (blockIdx.x & 3) * 128 + threadIdx.x;
  int col = hh * VE + vv;

  float Sq = 0.f, Sk = 0.f;
#pragma unroll
  for (int c = 0; c < NCHUNK; ++c) {
    Sq += ws[OFF_PQ + c * VD + col];
    Sk += ws[OFF_PK + c * VD + col];
  }
  float v1 = vc[col*3+0]*vcw[col*4+0] + vc[col*3+1]*vcw[col*4+1] + vc[col*3+2]*vcw[col*4+2]
           + ws[OFF_V + col]*vcw[col*4+3];
  float vh = siluf_(v1);
  float a  = sigmoidf_(ws[OFF_AB + hh]);
  float bb = sigmoidf_(ws[OFF_AB + 16 + hh]);
  float kq = ws[OFF_KQ + hh];
  // out = a*Sq + b*kq*(vh - a*Sk)
  ws[OFF_OUT + col] = a * Sq + bb * kq * (vh - a * Sk);
}

// --------------- Kernel D: output GEMV  d_out = Wo @ out ---------------------
// wave per row, 4 waves/block, 4096 rows. Wo (134 MB) is read exactly once
// per iteration -> NON-TEMPORAL loads so it never evicts the k1 weights
// from the Infinity Cache. `out` (32 KB, reused by 1024 blocks) stays cached.
__global__ __launch_bounds__(256) void kD_gemv_out(
    const float* __restrict__ Wo, const float* __restrict__ ws,
    float* __restrict__ dout) {
  int tid = threadIdx.x;
  int wave = tid >> 6, lane = tid & 63;
  int row = blockIdx.x * 4 + wave;
  const f4_t* r4 = (const f4_t*)(Wo + (size_t)row * VD);
  const float4* o4 = (const float4*)(ws + OFF_OUT);

  float acc = 0.f;
#pragma unroll
  for (int j = 0; j < 32; ++j) {
    f4_t  w  = __builtin_nontemporal_load(&r4[j * 64 + lane]);
    float4 ov = o4[j * 64 + lane];
    acc += w.x * ov.x + w.y * ov.y + w.z * ov.z + w.w * ov.w;
  }
#pragma unroll
  for (int off = 32; off; off >>= 1) acc += __shfl_xor(acc, off, 64);
  if (lane == 0) dout[row] = acc;
}

extern "C" void kernel_launch(void* const* d_in, const int* in_sizes, int n_in,
                              void* d_out, int out_size, void* d_ws, size_t ws_size,
                              hipStream_t stream) {
  const float* hvec = (const float*)d_in[0];
  const float* Wq   = (const float*)d_in[1];
  const float* Wk   = (const float*)d_in[2];
  const float* Wv   = (const float*)d_in[3];
  const float* Wo   = (const float*)d_in[4];
  const float* Wa   = (const float*)d_in[5];
  const float* Wb   = (const float*)d_in[6];
  const float* qcw  = (const float*)d_in[7];
  const float* kcw  = (const float*)d_in[8];
  const float* vcw  = (const float*)d_in[9];
  const float* qc   = (const float*)d_in[10];
  const float* kc   = (const float*)d_in[11];
  const float* vc   = (const float*)d_in[12];
  const float* state= (const float*)d_in[13];
  float* ws  = (float*)d_ws;
  float* out = (float*)d_out;

  k1_gemv_all<<<4104, 256, 0, stream>>>(hvec, Wq, Wk, Wv, Wa, Wb, ws);
  kB_state<<<256, 512, 0, stream>>>(qcw, kcw, qc, kc, state, ws);
  kC_combine<<<64, 128, 0, stream>>>(vcw, vc, ws);
  kD_gemv_out<<<1024, 256, 0, stream>>>(Wo, ws, out);
}